// Round 13
// baseline (304.880 us; speedup 1.0000x reference)
//
#include <hip/hip_runtime.h>
#include <hip/hip_bf16.h>
#include <stdint.h>

// MultiHeadAttention: B=32, NQ=T=1024, E=128, H=8, dk=dv=16
// Inputs FLOAT32, output FLOAT32. Internal bf16 MFMA.
// S^T via mfma_f32_32x32x16_bf16 (K=16 == dk); PV + denom via 16x16x32.
// Softmax exp2-domain, fixed max -18 in MFMA C operand. LUT AND-masking.
// attn: 64 queries/wave (2 q-groups of 32), 2-phase pipelined t-loop.
// Launch 1 fuses Q/K/V projection blocks + mask-pack blocks in ONE grid so
// the 134 MB mask read (pure HBM) overlaps the MFMA-bound projections.
// 3 launches: projqkv+maskpack -> flash-attn -> out-proj.

typedef __attribute__((ext_vector_type(8))) short bf16x8;    // MFMA A/B frag
typedef __attribute__((ext_vector_type(4))) float f32x4;     // 16x16 C/D frag
typedef __attribute__((ext_vector_type(16))) float f32x16;   // 32x32 C/D frag

#define NEGBIG (-1e30f)
#define QSCALE 0.36067376022224085f   // (1/sqrt(16)) * log2(e)
#define EXP2(x) __builtin_amdgcn_exp2f(x)   // raw v_exp_f32 (2^x)
#define PSTRIDE 68                     // ushorts; 34 dwords = 2 mod 32 banks

__device__ __forceinline__ unsigned short f2bf(float x) {
  union { __hip_bfloat16 h; unsigned short u; } cv;
  cv.h = __float2bfloat16(x);
  return cv.u;
}
// pack two f32 -> two bf16 (round-half-up) in one dword: low=a, high=b
__device__ __forceinline__ unsigned int pk2bf(float a, float b) {
  unsigned int ua = __float_as_uint(a) + 0x8000u;
  unsigned int ub = __float_as_uint(b) + 0x8000u;
  return __builtin_amdgcn_perm(ub, ua, 0x07060302u);
}

// ---------------- fused Q/K/V projection + mask packing (one grid) ----------------
// blocks 0..1535: sel = x>>9 -> Q / K / V^T projection (64-row tile each)
// blocks 1536..9727: mask pack (16 elems/thread -> bit per (b,q,t))
__global__ __launch_bounds__(256) void projmask_k(const float* __restrict__ qp,
                                                  const float* __restrict__ hp,
                                                  const float* __restrict__ wqp,
                                                  const float* __restrict__ wkp,
                                                  const float* __restrict__ wvp,
                                                  const void* __restrict__ mask,
                                                  unsigned short* __restrict__ Qb,
                                                  unsigned short* __restrict__ Kb,
                                                  unsigned short* __restrict__ Vt,
                                                  unsigned long long* __restrict__ mp64) {
  __shared__ unsigned short WtLds[128 * 136];
  __shared__ __align__(16) unsigned short Cxf[9216];
  const int tid = threadIdx.x;

  if (blockIdx.x >= 1536) {   // ---------- mask-pack blocks ----------
    const int bx = blockIdx.x - 1536;
    unsigned short* mlds = WtLds;  // reuse LDS
    const unsigned int* mi = (const unsigned int*)mask;
    unsigned int accv = 0;
    #pragma unroll
    for (int k = 0; k < 16; ++k) accv |= mi[k * 251];
    const bool bytemode = accv > 1u;

    const long long i0 = ((long long)bx * 256 + tid) * 16;
    unsigned int v = 0;
    if (bytemode) {
      int4 w = *(const int4*)((const unsigned char*)mask + i0);
      unsigned int ws[4] = {(unsigned)w.x, (unsigned)w.y, (unsigned)w.z, (unsigned)w.w};
      #pragma unroll
      for (int d = 0; d < 4; ++d)
        #pragma unroll
        for (int j = 0; j < 4; ++j)
          v |= (((ws[d] >> (8*j)) & 0xFFu) ? 1u : 0u) << (d*4 + j);
    } else {
      const int4* mp4 = (const int4*)((const int*)mask + i0);
      #pragma unroll
      for (int d = 0; d < 4; ++d) {
        int4 w = mp4[d];
        v |= (w.x ? 1u : 0u) << (d*4 + 0);
        v |= (w.y ? 1u : 0u) << (d*4 + 1);
        v |= (w.z ? 1u : 0u) << (d*4 + 2);
        v |= (w.w ? 1u : 0u) << (d*4 + 3);
      }
    }
    mlds[tid] = (unsigned short)v;
    __syncthreads();
    if (tid < 64)
      mp64[(long long)bx * 64 + tid] = ((const unsigned long long*)mlds)[tid];
    return;
  }

  // ---------- projection blocks ----------
  const int wave = tid >> 6, lane = tid & 63;
  const int llo4 = lane & 15, lhi4 = lane >> 4;
  const int xb = blockIdx.x & 511;
  const int sel = blockIdx.x >> 9;
  const int m0 = xb * 64;
  const int b = m0 >> 10, row0 = m0 & 1023;
  const float* A = (sel == 0) ? qp : hp;
  const float* W = (sel == 0) ? wqp : (sel == 1) ? wkp : wvp;
  const float wscale = (sel == 0) ? QSCALE : 1.0f;

  #pragma unroll
  for (int i = 0; i < 8; ++i) {
    int base = (tid + i * 256) * 8;
    float4 w0 = *(const float4*)&W[base];
    float4 w1 = *(const float4*)&W[base + 4];
    float wv8[8] = {w0.x, w0.y, w0.z, w0.w, w1.x, w1.y, w1.z, w1.w};
    #pragma unroll
    for (int j = 0; j < 8; ++j) {
      int idx = base + j;
      int h = idx >> 11, e = (idx >> 4) & 127, kk = idx & 15;
      WtLds[(h*16 + kk) * 136 + e] = f2bf(wv8[j] * wscale);
    }
  }
  #pragma unroll
  for (int i = 0; i < 4; ++i) {
    int r = (tid >> 4) + i * 16;
    int c = (tid & 15) * 8;
    float4 a0 = *(const float4*)&A[(m0 + r) * 128 + c];
    float4 a1 = *(const float4*)&A[(m0 + r) * 128 + c + 4];
    bf16x8 a8;
    a8[0] = (short)f2bf(a0.x); a8[1] = (short)f2bf(a0.y);
    a8[2] = (short)f2bf(a0.z); a8[3] = (short)f2bf(a0.w);
    a8[4] = (short)f2bf(a1.x); a8[5] = (short)f2bf(a1.y);
    a8[6] = (short)f2bf(a1.z); a8[7] = (short)f2bf(a1.w);
    *(bf16x8*)&Cxf[r * 136 + c] = a8;
  }
  __syncthreads();

  const int n0 = wave * 32;
  f32x4 acc[4][2] = {};
  #pragma unroll
  for (int kk = 0; kk < 128; kk += 32) {
    bf16x8 af[4], bfr[2];
    #pragma unroll
    for (int mi2 = 0; mi2 < 4; ++mi2)
      af[mi2] = *(const bf16x8*)&Cxf[(mi2*16 + llo4)*136 + kk + lhi4*8];
    #pragma unroll
    for (int ni = 0; ni < 2; ++ni)
      bfr[ni] = *(const bf16x8*)&WtLds[(n0 + ni*16 + llo4)*136 + kk + lhi4*8];
    #pragma unroll
    for (int mi2 = 0; mi2 < 4; ++mi2)
      #pragma unroll
      for (int ni = 0; ni < 2; ++ni)
        acc[mi2][ni] = __builtin_amdgcn_mfma_f32_16x16x32_bf16(af[mi2], bfr[ni], acc[mi2][ni], 0, 0, 0);
  }

  __syncthreads();
  if (sel < 2) {
    unsigned short* Cb = sel ? Kb : Qb;
    #pragma unroll
    for (int mi2 = 0; mi2 < 4; ++mi2)
      #pragma unroll
      for (int ni = 0; ni < 2; ++ni) {
        int n = n0 + ni*16 + llo4;
        #pragma unroll
        for (int r = 0; r < 4; ++r)
          Cxf[(mi2*16 + lhi4*4 + r)*136 + n] = f2bf(acc[mi2][ni][r]);
      }
    __syncthreads();
    #pragma unroll
    for (int it = 0; it < 4; ++it) {
      int u = tid + it*256;
      int h = u >> 7, rk = u & 127, row = rk >> 1, kh = rk & 1;
      bf16x8 vv = *(const bf16x8*)&Cxf[row*136 + h*16 + kh*8];
      *(bf16x8*)&Cb[((b*8 + h)*1024 + row0 + row)*16 + kh*8] = vv;
    }
  } else {
    #pragma unroll
    for (int mi2 = 0; mi2 < 4; ++mi2)
      #pragma unroll
      for (int ni = 0; ni < 2; ++ni) {
        int n = n0 + ni*16 + llo4;
        ushort4 pk;
        pk.x = f2bf(acc[mi2][ni][0]); pk.y = f2bf(acc[mi2][ni][1]);
        pk.z = f2bf(acc[mi2][ni][2]); pk.w = f2bf(acc[mi2][ni][3]);
        *(ushort4*)&Cxf[n*72 + mi2*16 + lhi4*4] = pk;
      }
    __syncthreads();
    #pragma unroll
    for (int it = 0; it < 4; ++it) {
      int u = tid + it*256;
      int n = u >> 3, tc = u & 7;
      int h = n >> 4, k = n & 15;
      bf16x8 vv = *(const bf16x8*)&Cxf[n*72 + tc*8];
      *(bf16x8*)&Vt[((b*8 + h)*16 + k)*1024 + row0 + tc*8] = vv;
    }
  }
}

// ---------------- flash attention (64q/wave, 32x32 S-MFMA, LUT mask) ----------------
// grid (NQ/256, B, H); wave w owns queries x*256 + w*64 .. +63 of head z.
__global__ __launch_bounds__(256) void attn_k(const unsigned short* __restrict__ Qb,
                                              const unsigned short* __restrict__ Kb,
                                              const unsigned short* __restrict__ Vtb,
                                              const unsigned long long* __restrict__ mp64,
                                              unsigned short* __restrict__ heads) {
  __shared__ __align__(16) unsigned short Plds[4][64 * PSTRIDE]; // per-wave [q64][t64]
  __shared__ __align__(8) uint2 mlut[16];  // nibble -> 4 halfword AND-masks
  const int tid = threadIdx.x;
  const int wave = tid >> 6, lane = tid & 63;
  const int llo4 = lane & 15, lhi4 = lane >> 4;
  const int llo5 = lane & 31, lhi5 = lane >> 5;
  const int q0 = blockIdx.x * 256 + wave * 64;
  const int b  = blockIdx.y;
  const int h  = blockIdx.z;
  const int bh = b * 8 + h;
  unsigned short* Pw = &Plds[wave][0];
  const unsigned long long* mp_base = &mp64[((b << 10) + q0 + llo5) * 16];
  // q-group 1 offset: +32 q rows = +512 u64
  const unsigned short* Kbase = &Kb[(bh * 1024 + llo5) * 16 + lhi5 * 8];
  const unsigned short* Vbase = &Vtb[(bh * 16 + llo4) * 1024 + lhi4 * 8];

  if (tid < 16) {
    unsigned int n = tid;
    unsigned int h0 = (n & 1u) ? 0u : 0xFFFFu;
    unsigned int h1 = (n & 2u) ? 0u : 0xFFFFu;
    unsigned int h2 = (n & 4u) ? 0u : 0xFFFFu;
    unsigned int h3 = (n & 8u) ? 0u : 0xFFFFu;
    mlut[tid] = make_uint2(h0 | (h1 << 16), h2 | (h3 << 16));
  }
  __syncthreads();

  // Q^T B-frags: q-group qg covers q = q0 + qg*32 + llo5
  bf16x8 qf[2];
  #pragma unroll
  for (int qg = 0; qg < 2; ++qg)
    qf[qg] = *(const bf16x8*)&Qb[(bh * 1024 + q0 + qg*32 + llo5) * 16 + lhi5 * 8];

  bf16x8 ones;
  #pragma unroll
  for (int j = 0; j < 8; ++j) ones[j] = (short)0x3F80;  // bf16 1.0
  f32x16 cb16;
  #pragma unroll
  for (int j = 0; j < 16; ++j) cb16[j] = -18.f;

  f32x4 ot[4] = {};    // O^T per 16-q frag (qn = q_local/16): lane q=llo4, v=lhi4*4+reg
  f32x4 lacc[4] = {};  // denominators

  // 2-phase pipeline buffers
  bf16x8 kfb[2][2], vfb[2][2];
  unsigned long long mwb[2][2];   // [slot][qgroup]

  #pragma unroll
  for (int tt = 0; tt < 2; ++tt)
    kfb[0][tt] = *(const bf16x8*)&Kbase[(tt*32) * 16];
  #pragma unroll
  for (int kt = 0; kt < 2; ++kt)
    vfb[0][kt] = *(const bf16x8*)&Vbase[kt*32];
  mwb[0][0] = mp_base[0];
  mwb[0][1] = mp_base[512];

  #pragma unroll 2
  for (int tw = 0; tw < 16; ++tw) {
    const int cur = tw & 1, nxt = cur ^ 1;
    const int twn = (tw < 15) ? tw + 1 : 15;
    const int t0n = twn * 64;
    // prefetch tile tw+1 (overlaps all compute below)
    #pragma unroll
    for (int tt = 0; tt < 2; ++tt)
      kfb[nxt][tt] = *(const bf16x8*)&Kbase[(t0n + tt*32) * 16];
    #pragma unroll
    for (int kt = 0; kt < 2; ++kt)
      vfb[nxt][kt] = *(const bf16x8*)&Vbase[t0n + kt*32];
    mwb[nxt][0] = mp_base[twn];
    mwb[nxt][1] = mp_base[512 + twn];

    // per q-group: S^T = K*Q^T - 18, exp2, LUT-mask, pack to LDS
    #pragma unroll
    for (int qg = 0; qg < 2; ++qg) {
      f32x16 st[2];
      #pragma unroll
      for (int tt = 0; tt < 2; ++tt)
        st[tt] = __builtin_amdgcn_mfma_f32_32x32x16_bf16(kfb[cur][tt], qf[qg], cb16, 0, 0, 0);

      const unsigned int mwlo = (unsigned int)mwb[cur][qg];
      const unsigned int mwhi = (unsigned int)(mwb[cur][qg] >> 32);
      #pragma unroll
      for (int tt = 0; tt < 2; ++tt) {
        const unsigned int m32 = (tt ? mwhi : mwlo) >> (lhi5 * 4);
        #pragma unroll
        for (int g = 0; g < 4; ++g) {
          unsigned int nib = (m32 >> (g*8)) & 0xFu;
          uint2 am = mlut[nib];
          uint2 d;
          d.x = pk2bf(EXP2(st[tt][g*4 + 0]), EXP2(st[tt][g*4 + 1])) & am.x;
          d.y = pk2bf(EXP2(st[tt][g*4 + 2]), EXP2(st[tt][g*4 + 3])) & am.y;
          *(uint2*)&Pw[(qg*32 + llo5) * PSTRIDE + tt*32 + lhi5*4 + g*8] = d;
        }
      }
    }

    // O^T += V^T * P^T ; l += ones * P^T  (P read as two b64s, stride 68)
    #pragma unroll
    for (int kt = 0; kt < 2; ++kt) {
      #pragma unroll
      for (int qn = 0; qn < 4; ++qn) {
        const unsigned short* pp = &Pw[(qn*16 + llo4) * PSTRIDE + kt*32 + lhi4*8];
        uint2 p0 = *(const uint2*)pp;
        uint2 p1 = *(const uint2*)(pp + 4);
        union { uint2 u[2]; bf16x8 v; } pf;
        pf.u[0] = p0; pf.u[1] = p1;
        ot[qn]   = __builtin_amdgcn_mfma_f32_16x16x32_bf16(vfb[cur][kt], pf.v, ot[qn], 0, 0, 0);
        lacc[qn] = __builtin_amdgcn_mfma_f32_16x16x32_bf16(ones,        pf.v, lacc[qn], 0, 0, 0);
      }
    }
  }

  #pragma unroll
  for (int qn = 0; qn < 4; ++qn) {
    float l = lacc[qn][0];
    float inv = l > 0.f ? 1.f / l : 0.f;
    f32x4 o = ot[qn] * inv;
    uint2 d;
    d.x = pk2bf(o[0], o[1]);
    d.y = pk2bf(o[2], o[3]);
    *(uint2*)&heads[((b << 10) + q0 + qn*16 + llo4) * 128 + h*16 + lhi4*4] = d;
  }
}

// ---------------- output projection ----------------
__global__ __launch_bounds__(256) void outproj_k(const unsigned short* __restrict__ Av,
                                                 const float* __restrict__ W,
                                                 float* __restrict__ Co) {
  __shared__ unsigned short WtLds[128 * 136];
  __shared__ __align__(16) unsigned short Cxf[9216];
  const int tid = threadIdx.x;
  const int wave = tid >> 6, lane = tid & 63;
  const int llo4 = lane & 15, lhi4 = lane >> 4;
  const int m0 = blockIdx.x * 64;

  #pragma unroll
  for (int i = 0; i < 8; ++i) {
    int base = (tid + i * 256) * 8;
    float4 w0 = *(const float4*)&W[base];
    float4 w1 = *(const float4*)&W[base + 4];
    float wv8[8] = {w0.x, w0.y, w0.z, w0.w, w1.x, w1.y, w1.z, w1.w};
    #pragma unroll
    for (int j = 0; j < 8; ++j) {
      int idx = base + j;
      WtLds[(idx & 127) * 136 + (idx >> 7)] = f2bf(wv8[j]);
    }
  }
  #pragma unroll
  for (int i = 0; i < 4; ++i) {
    int r = (tid >> 4) + i * 16;
    int c = (tid & 15) * 8;
    *(bf16x8*)&Cxf[r * 136 + c] = *(const bf16x8*)&Av[(m0 + r) * 128 + c];
  }
  __syncthreads();

  const int n0 = wave * 32;
  f32x4 acc[4][2] = {};
  #pragma unroll
  for (int kk = 0; kk < 128; kk += 32) {
    bf16x8 af[4], bfr[2];
    #pragma unroll
    for (int mi2 = 0; mi2 < 4; ++mi2)
      af[mi2] = *(const bf16x8*)&Cxf[(mi2*16 + llo4)*136 + kk + lhi4*8];
    #pragma unroll
    for (int ni = 0; ni < 2; ++ni)
      bfr[ni] = *(const bf16x8*)&WtLds[(n0 + ni*16 + llo4)*136 + kk + lhi4*8];
    #pragma unroll
    for (int mi2 = 0; mi2 < 4; ++mi2)
      #pragma unroll
      for (int ni = 0; ni < 2; ++ni)
        acc[mi2][ni] = __builtin_amdgcn_mfma_f32_16x16x32_bf16(af[mi2], bfr[ni], acc[mi2][ni], 0, 0, 0);
  }
  #pragma unroll
  for (int mi2 = 0; mi2 < 4; ++mi2)
    #pragma unroll
    for (int ni = 0; ni < 2; ++ni) {
      int n = n0 + ni*16 + llo4;
      int mbase = m0 + mi2*16 + lhi4*4;
      #pragma unroll
      for (int r = 0; r < 4; ++r)
        Co[(mbase + r) * 128 + n] = acc[mi2][ni][r];
    }
}

extern "C" void kernel_launch(void* const* d_in, const int* in_sizes, int n_in,
                              void* d_out, int out_size, void* d_ws, size_t ws_size,
                              hipStream_t stream) {
  const float* q  = (const float*)d_in[0];
  const float* hh = (const float*)d_in[1];
  const void*  mk = d_in[2];
  const float* wq = (const float*)d_in[3];
  const float* wk = (const float*)d_in[4];
  const float* wv = (const float*)d_in[5];
  const float* wo = (const float*)d_in[6];
  float* out = (float*)d_out;

  unsigned short* Qb = (unsigned short*)d_ws;       // [B][H][NQ][16]  8.4 MB
  unsigned short* Kb = Qb + 32*8*1024*16;           // [B][H][T][16]   8.4 MB
  unsigned short* Vt = Kb + 32*8*1024*16;           // [B][H][16][T]   8.4 MB
  unsigned short* hd = Vt + 32*8*1024*16;           // [B*NQ][128]     8.4 MB
  unsigned long long* mp64 = (unsigned long long*)(hd + 32768*128); // 4.2 MB

  projmask_k<<<9728, 256, 0, stream>>>(q, hh, wq, wk, wv, mk, Qb, Kb, Vt, mp64);
  attn_k<<<dim3(4, 32, 8), 256, 0, stream>>>(Qb, Kb, Vt, mp64, hd);
  outproj_k<<<512, 256, 0, stream>>>(hd, wo, out);
}

// Round 14
// 301.797 us; speedup vs baseline: 1.0102x; 1.0102x over previous
//
#include <hip/hip_runtime.h>
#include <hip/hip_bf16.h>
#include <stdint.h>

// MultiHeadAttention: B=32, NQ=T=1024, E=128, H=8, dk=dv=16
// Inputs FLOAT32, output FLOAT32. Internal bf16 MFMA.
// S^T via mfma_f32_32x32x16_bf16 (K=16 == dk); PV + denom via 16x16x32.
// Softmax exp2-domain, fixed max -18 in MFMA C operand. LUT AND-masking.
// attn: 32 q/wave, ONE WAVE PER BLOCK (8192 blocks) for max occupancy;
// P packed with truncation (self-normalizing through the shared denominator).
// Launch 1 fuses Q/K/V projection blocks + mask-pack blocks in ONE grid so
// the 134 MB mask read (pure HBM) overlaps the MFMA-bound projections.
// 3 launches: projqkv+maskpack -> flash-attn -> out-proj.

typedef __attribute__((ext_vector_type(8))) short bf16x8;    // MFMA A/B frag
typedef __attribute__((ext_vector_type(4))) float f32x4;     // 16x16 C/D frag
typedef __attribute__((ext_vector_type(16))) float f32x16;   // 32x32 C/D frag

#define NEGBIG (-1e30f)
#define QSCALE 0.36067376022224085f   // (1/sqrt(16)) * log2(e)
#define EXP2(x) __builtin_amdgcn_exp2f(x)   // raw v_exp_f32 (2^x)
#define PSTRIDE 68                     // ushorts; 34 dwords = 2 mod 32 banks

__device__ __forceinline__ unsigned short f2bf(float x) {
  union { __hip_bfloat16 h; unsigned short u; } cv;
  cv.h = __float2bfloat16(x);
  return cv.u;
}
// pack two f32 -> two bf16 (round-half-up): low=a, high=b
__device__ __forceinline__ unsigned int pk2bf(float a, float b) {
  unsigned int ua = __float_as_uint(a) + 0x8000u;
  unsigned int ub = __float_as_uint(b) + 0x8000u;
  return __builtin_amdgcn_perm(ub, ua, 0x07060302u);
}
// pack two f32 -> two bf16 (truncate; 1 instr): low=a, high=b
__device__ __forceinline__ unsigned int pk2bf_t(float a, float b) {
  return __builtin_amdgcn_perm(__float_as_uint(b), __float_as_uint(a), 0x07060302u);
}

// ---------------- fused Q/K/V projection + mask packing (one grid) ----------------
// blocks 0..1535: sel = x>>9 -> Q / K / V^T projection (64-row tile each)
// blocks 1536..9727: mask pack (16 elems/thread -> bit per (b,q,t))
__global__ __launch_bounds__(256) void projmask_k(const float* __restrict__ qp,
                                                  const float* __restrict__ hp,
                                                  const float* __restrict__ wqp,
                                                  const float* __restrict__ wkp,
                                                  const float* __restrict__ wvp,
                                                  const void* __restrict__ mask,
                                                  unsigned short* __restrict__ Qb,
                                                  unsigned short* __restrict__ Kb,
                                                  unsigned short* __restrict__ Vt,
                                                  unsigned long long* __restrict__ mp64) {
  __shared__ unsigned short WtLds[128 * 136];
  __shared__ __align__(16) unsigned short Cxf[9216];
  const int tid = threadIdx.x;

  if (blockIdx.x >= 1536) {   // ---------- mask-pack blocks ----------
    const int bx = blockIdx.x - 1536;
    unsigned short* mlds = WtLds;  // reuse LDS
    const unsigned int* mi = (const unsigned int*)mask;
    unsigned int accv = 0;
    #pragma unroll
    for (int k = 0; k < 16; ++k) accv |= mi[k * 251];
    const bool bytemode = accv > 1u;

    const long long i0 = ((long long)bx * 256 + tid) * 16;
    unsigned int v = 0;
    if (bytemode) {
      int4 w = *(const int4*)((const unsigned char*)mask + i0);
      unsigned int ws[4] = {(unsigned)w.x, (unsigned)w.y, (unsigned)w.z, (unsigned)w.w};
      #pragma unroll
      for (int d = 0; d < 4; ++d)
        #pragma unroll
        for (int j = 0; j < 4; ++j)
          v |= (((ws[d] >> (8*j)) & 0xFFu) ? 1u : 0u) << (d*4 + j);
    } else {
      const int4* mp4 = (const int4*)((const int*)mask + i0);
      #pragma unroll
      for (int d = 0; d < 4; ++d) {
        int4 w = mp4[d];
        v |= (w.x ? 1u : 0u) << (d*4 + 0);
        v |= (w.y ? 1u : 0u) << (d*4 + 1);
        v |= (w.z ? 1u : 0u) << (d*4 + 2);
        v |= (w.w ? 1u : 0u) << (d*4 + 3);
      }
    }
    mlds[tid] = (unsigned short)v;
    __syncthreads();
    if (tid < 64)
      mp64[(long long)bx * 64 + tid] = ((const unsigned long long*)mlds)[tid];
    return;
  }

  // ---------- projection blocks ----------
  const int wave = tid >> 6, lane = tid & 63;
  const int llo4 = lane & 15, lhi4 = lane >> 4;
  const int xb = blockIdx.x & 511;
  const int sel = blockIdx.x >> 9;
  const int m0 = xb * 64;
  const int b = m0 >> 10, row0 = m0 & 1023;
  const float* A = (sel == 0) ? qp : hp;
  const float* W = (sel == 0) ? wqp : (sel == 1) ? wkp : wvp;
  const float wscale = (sel == 0) ? QSCALE : 1.0f;

  #pragma unroll
  for (int i = 0; i < 8; ++i) {
    int base = (tid + i * 256) * 8;
    float4 w0 = *(const float4*)&W[base];
    float4 w1 = *(const float4*)&W[base + 4];
    float wv8[8] = {w0.x, w0.y, w0.z, w0.w, w1.x, w1.y, w1.z, w1.w};
    #pragma unroll
    for (int j = 0; j < 8; ++j) {
      int idx = base + j;
      int h = idx >> 11, e = (idx >> 4) & 127, kk = idx & 15;
      WtLds[(h*16 + kk) * 136 + e] = f2bf(wv8[j] * wscale);
    }
  }
  #pragma unroll
  for (int i = 0; i < 4; ++i) {
    int r = (tid >> 4) + i * 16;
    int c = (tid & 15) * 8;
    float4 a0 = *(const float4*)&A[(m0 + r) * 128 + c];
    float4 a1 = *(const float4*)&A[(m0 + r) * 128 + c + 4];
    bf16x8 a8;
    a8[0] = (short)f2bf(a0.x); a8[1] = (short)f2bf(a0.y);
    a8[2] = (short)f2bf(a0.z); a8[3] = (short)f2bf(a0.w);
    a8[4] = (short)f2bf(a1.x); a8[5] = (short)f2bf(a1.y);
    a8[6] = (short)f2bf(a1.z); a8[7] = (short)f2bf(a1.w);
    *(bf16x8*)&Cxf[r * 136 + c] = a8;
  }
  __syncthreads();

  const int n0 = wave * 32;
  f32x4 acc[4][2] = {};
  #pragma unroll
  for (int kk = 0; kk < 128; kk += 32) {
    bf16x8 af[4], bfr[2];
    #pragma unroll
    for (int mi2 = 0; mi2 < 4; ++mi2)
      af[mi2] = *(const bf16x8*)&Cxf[(mi2*16 + llo4)*136 + kk + lhi4*8];
    #pragma unroll
    for (int ni = 0; ni < 2; ++ni)
      bfr[ni] = *(const bf16x8*)&WtLds[(n0 + ni*16 + llo4)*136 + kk + lhi4*8];
    #pragma unroll
    for (int mi2 = 0; mi2 < 4; ++mi2)
      #pragma unroll
      for (int ni = 0; ni < 2; ++ni)
        acc[mi2][ni] = __builtin_amdgcn_mfma_f32_16x16x32_bf16(af[mi2], bfr[ni], acc[mi2][ni], 0, 0, 0);
  }

  __syncthreads();
  if (sel < 2) {
    unsigned short* Cb = sel ? Kb : Qb;
    #pragma unroll
    for (int mi2 = 0; mi2 < 4; ++mi2)
      #pragma unroll
      for (int ni = 0; ni < 2; ++ni) {
        int n = n0 + ni*16 + llo4;
        #pragma unroll
        for (int r = 0; r < 4; ++r)
          Cxf[(mi2*16 + lhi4*4 + r)*136 + n] = f2bf(acc[mi2][ni][r]);
      }
    __syncthreads();
    #pragma unroll
    for (int it = 0; it < 4; ++it) {
      int u = tid + it*256;
      int h = u >> 7, rk = u & 127, row = rk >> 1, kh = rk & 1;
      bf16x8 vv = *(const bf16x8*)&Cxf[row*136 + h*16 + kh*8];
      *(bf16x8*)&Cb[((b*8 + h)*1024 + row0 + row)*16 + kh*8] = vv;
    }
  } else {
    #pragma unroll
    for (int mi2 = 0; mi2 < 4; ++mi2)
      #pragma unroll
      for (int ni = 0; ni < 2; ++ni) {
        int n = n0 + ni*16 + llo4;
        ushort4 pk;
        pk.x = f2bf(acc[mi2][ni][0]); pk.y = f2bf(acc[mi2][ni][1]);
        pk.z = f2bf(acc[mi2][ni][2]); pk.w = f2bf(acc[mi2][ni][3]);
        *(ushort4*)&Cxf[n*72 + mi2*16 + lhi4*4] = pk;
      }
    __syncthreads();
    #pragma unroll
    for (int it = 0; it < 4; ++it) {
      int u = tid + it*256;
      int n = u >> 3, tc = u & 7;
      int h = n >> 4, k = n & 15;
      bf16x8 vv = *(const bf16x8*)&Cxf[n*72 + tc*8];
      *(bf16x8*)&Vt[((b*8 + h)*16 + k)*1024 + row0 + tc*8] = vv;
    }
  }
}

// ---------------- flash attention (1 wave/block, 32x32 S-MFMA, LUT mask) ----------------
// grid (NQ/32, B, H); the single wave owns queries x*32 .. +31 of head z.
__global__ __launch_bounds__(64) void attn_k(const unsigned short* __restrict__ Qb,
                                             const unsigned short* __restrict__ Kb,
                                             const unsigned short* __restrict__ Vtb,
                                             const unsigned long long* __restrict__ mp64,
                                             unsigned short* __restrict__ heads) {
  __shared__ __align__(16) unsigned short Pw[32 * PSTRIDE]; // [q32][t64]
  __shared__ __align__(8) uint2 mlut[16];  // nibble -> 4 halfword AND-masks
  const int lane = threadIdx.x;
  const int llo4 = lane & 15, lhi4 = lane >> 4;
  const int llo5 = lane & 31, lhi5 = lane >> 5;
  const int q0 = blockIdx.x * 32;
  const int b  = blockIdx.y;
  const int h  = blockIdx.z;
  const int bh = b * 8 + h;
  const unsigned long long* mp_base = &mp64[((b << 10) + q0 + llo5) * 16];
  const unsigned short* Kbase = &Kb[(bh * 1024 + llo5) * 16 + lhi5 * 8];
  const unsigned short* Vbase = &Vtb[(bh * 16 + llo4) * 1024 + lhi4 * 8];

  if (lane < 16) {
    unsigned int n = lane;
    unsigned int h0 = (n & 1u) ? 0u : 0xFFFFu;
    unsigned int h1 = (n & 2u) ? 0u : 0xFFFFu;
    unsigned int h2 = (n & 4u) ? 0u : 0xFFFFu;
    unsigned int h3 = (n & 8u) ? 0u : 0xFFFFu;
    mlut[lane] = make_uint2(h0 | (h1 << 16), h2 | (h3 << 16));
  }
  // single wave: LDS write->read ordering handled by lgkmcnt, no barrier needed

  // Q^T B-frag (32 q wide, k = lhi5*8+j covers full dk=16)
  bf16x8 qf = *(const bf16x8*)&Qb[(bh * 1024 + q0 + llo5) * 16 + lhi5 * 8];

  bf16x8 ones;
  #pragma unroll
  for (int j = 0; j < 8; ++j) ones[j] = (short)0x3F80;  // bf16 1.0
  f32x16 cb16;
  #pragma unroll
  for (int j = 0; j < 16; ++j) cb16[j] = -18.f;

  f32x4 ot[2] = {};    // O^T per 16-q frag: lane q=llo4, v=lhi4*4+reg
  f32x4 lacc[2] = {};  // denominators

  // 2-phase pipeline buffers
  bf16x8 kfb[2][2], vfb[2][2];
  unsigned long long mwb[2];

  #pragma unroll
  for (int tt = 0; tt < 2; ++tt)
    kfb[0][tt] = *(const bf16x8*)&Kbase[(tt*32) * 16];
  #pragma unroll
  for (int kt = 0; kt < 2; ++kt)
    vfb[0][kt] = *(const bf16x8*)&Vbase[kt*32];
  mwb[0] = mp_base[0];

  #pragma unroll 2
  for (int tw = 0; tw < 16; ++tw) {
    const int cur = tw & 1, nxt = cur ^ 1;
    const int twn = (tw < 15) ? tw + 1 : 15;
    const int t0n = twn * 64;
    // prefetch tile tw+1
    #pragma unroll
    for (int tt = 0; tt < 2; ++tt)
      kfb[nxt][tt] = *(const bf16x8*)&Kbase[(t0n + tt*32) * 16];
    #pragma unroll
    for (int kt = 0; kt < 2; ++kt)
      vfb[nxt][kt] = *(const bf16x8*)&Vbase[t0n + kt*32];
    mwb[nxt] = mp_base[twn];

    // S^T = K*Q^T - 18 : two 32x32x16 MFMAs
    f32x16 st[2];
    #pragma unroll
    for (int tt = 0; tt < 2; ++tt)
      st[tt] = __builtin_amdgcn_mfma_f32_32x32x16_bf16(kfb[cur][tt], qf, cb16, 0, 0, 0);

    // exp2 + LUT AND-mask + pack P^T (truncating) to LDS [q=llo5][t stride 68]
    const unsigned int mwlo = (unsigned int)mwb[cur];
    const unsigned int mwhi = (unsigned int)(mwb[cur] >> 32);
    #pragma unroll
    for (int tt = 0; tt < 2; ++tt) {
      const unsigned int m32 = (tt ? mwhi : mwlo) >> (lhi5 * 4);
      #pragma unroll
      for (int g = 0; g < 4; ++g) {
        unsigned int nib = (m32 >> (g*8)) & 0xFu;
        uint2 am = mlut[nib];
        uint2 d;
        d.x = pk2bf_t(EXP2(st[tt][g*4 + 0]), EXP2(st[tt][g*4 + 1])) & am.x;
        d.y = pk2bf_t(EXP2(st[tt][g*4 + 2]), EXP2(st[tt][g*4 + 3])) & am.y;
        *(uint2*)&Pw[llo5 * PSTRIDE + tt*32 + lhi5*4 + g*8] = d;
      }
    }

    // O^T += V^T * P^T ; l += ones * P^T  (P read as two b64s, stride 68)
    #pragma unroll
    for (int kt = 0; kt < 2; ++kt) {
      #pragma unroll
      for (int qn = 0; qn < 2; ++qn) {
        const unsigned short* pp = &Pw[(qn*16 + llo4) * PSTRIDE + kt*32 + lhi4*8];
        uint2 p0 = *(const uint2*)pp;
        uint2 p1 = *(const uint2*)(pp + 4);
        union { uint2 u[2]; bf16x8 v; } pf;
        pf.u[0] = p0; pf.u[1] = p1;
        ot[qn]   = __builtin_amdgcn_mfma_f32_16x16x32_bf16(vfb[cur][kt], pf.v, ot[qn], 0, 0, 0);
        lacc[qn] = __builtin_amdgcn_mfma_f32_16x16x32_bf16(ones,        pf.v, lacc[qn], 0, 0, 0);
      }
    }
  }

  #pragma unroll
  for (int qn = 0; qn < 2; ++qn) {
    float l = lacc[qn][0];
    float inv = l > 0.f ? 1.f / l : 0.f;
    f32x4 o = ot[qn] * inv;
    uint2 d;
    d.x = pk2bf(o[0], o[1]);
    d.y = pk2bf(o[2], o[3]);
    *(uint2*)&heads[((b << 10) + q0 + qn*16 + llo4) * 128 + h*16 + lhi4*4] = d;
  }
}

// ---------------- output projection ----------------
__global__ __launch_bounds__(256) void outproj_k(const unsigned short* __restrict__ Av,
                                                 const float* __restrict__ W,
                                                 float* __restrict__ Co) {
  __shared__ unsigned short WtLds[128 * 136];
  __shared__ __align__(16) unsigned short Cxf[9216];
  const int tid = threadIdx.x;
  const int wave = tid >> 6, lane = tid & 63;
  const int llo4 = lane & 15, lhi4 = lane >> 4;
  const int m0 = blockIdx.x * 64;

  #pragma unroll
  for (int i = 0; i < 8; ++i) {
    int base = (tid + i * 256) * 8;
    float4 w0 = *(const float4*)&W[base];
    float4 w1 = *(const float4*)&W[base + 4];
    float wv8[8] = {w0.x, w0.y, w0.z, w0.w, w1.x, w1.y, w1.z, w1.w};
    #pragma unroll
    for (int j = 0; j < 8; ++j) {
      int idx = base + j;
      WtLds[(idx & 127) * 136 + (idx >> 7)] = f2bf(wv8[j]);
    }
  }
  #pragma unroll
  for (int i = 0; i < 4; ++i) {
    int r = (tid >> 4) + i * 16;
    int c = (tid & 15) * 8;
    *(bf16x8*)&Cxf[r * 136 + c] = *(const bf16x8*)&Av[(m0 + r) * 128 + c];
  }
  __syncthreads();

  const int n0 = wave * 32;
  f32x4 acc[4][2] = {};
  #pragma unroll
  for (int kk = 0; kk < 128; kk += 32) {
    bf16x8 af[4], bfr[2];
    #pragma unroll
    for (int mi2 = 0; mi2 < 4; ++mi2)
      af[mi2] = *(const bf16x8*)&Cxf[(mi2*16 + llo4)*136 + kk + lhi4*8];
    #pragma unroll
    for (int ni = 0; ni < 2; ++ni)
      bfr[ni] = *(const bf16x8*)&WtLds[(n0 + ni*16 + llo4)*136 + kk + lhi4*8];
    #pragma unroll
    for (int mi2 = 0; mi2 < 4; ++mi2)
      #pragma unroll
      for (int ni = 0; ni < 2; ++ni)
        acc[mi2][ni] = __builtin_amdgcn_mfma_f32_16x16x32_bf16(af[mi2], bfr[ni], acc[mi2][ni], 0, 0, 0);
  }
  #pragma unroll
  for (int mi2 = 0; mi2 < 4; ++mi2)
    #pragma unroll
    for (int ni = 0; ni < 2; ++ni) {
      int n = n0 + ni*16 + llo4;
      int mbase = m0 + mi2*16 + lhi4*4;
      #pragma unroll
      for (int r = 0; r < 4; ++r)
        Co[(mbase + r) * 128 + n] = acc[mi2][ni][r];
    }
}

extern "C" void kernel_launch(void* const* d_in, const int* in_sizes, int n_in,
                              void* d_out, int out_size, void* d_ws, size_t ws_size,
                              hipStream_t stream) {
  const float* q  = (const float*)d_in[0];
  const float* hh = (const float*)d_in[1];
  const void*  mk = d_in[2];
  const float* wq = (const float*)d_in[3];
  const float* wk = (const float*)d_in[4];
  const float* wv = (const float*)d_in[5];
  const float* wo = (const float*)d_in[6];
  float* out = (float*)d_out;

  unsigned short* Qb = (unsigned short*)d_ws;       // [B][H][NQ][16]  8.4 MB
  unsigned short* Kb = Qb + 32*8*1024*16;           // [B][H][T][16]   8.4 MB
  unsigned short* Vt = Kb + 32*8*1024*16;           // [B][H][16][T]   8.4 MB
  unsigned short* hd = Vt + 32*8*1024*16;           // [B*NQ][128]     8.4 MB
  unsigned long long* mp64 = (unsigned long long*)(hd + 32768*128); // 4.2 MB

  projmask_k<<<9728, 256, 0, stream>>>(q, hh, wq, wk, wv, mk, Qb, Kb, Vt, mp64);
  attn_k<<<dim3(32, 32, 8), 64, 0, stream>>>(Qb, Kb, Vt, mp64, hd);
  outproj_k<<<512, 256, 0, stream>>>(hd, wo, out);
}